// Round 5
// baseline (108.490 us; speedup 1.0000x reference)
//
#include <hip/hip_runtime.h>

// ---------------------------------------------------------------------------
// TwoLayerGCN on MI355X (gfx950).  B=4, N=2048, F=128, H=256, C=64.
//
//   deg_i = sum_j A_ij ; d_i = rsqrt(deg_i + 1)
//   w_ij  = [A_ij>0] * exp(lrelu(fs_i + fd_j)) * d_j * (1 + [i==j])
//   rs_i  = sum_j [A_ij>0] * exp(lrelu(fs_i + fd_j))
//   layer1: out1 = relu( (d_i/rs_i) * (W @ X) @ W1 + b1 )
//   layer2: node = (d_i/rs_i) * W2mat @ (out1 @ W2) + b2 ; graph = sum_i node
//
// R1: fused graph partials. R2: 1-barrier K-step pipeline + XOR swizzle.
// R3: 10 -> 5 kernels; out1 never touches HBM; rs_i folded into SpMM staging.
// R4: SpMMs' B-operands (XT / OW2T panels, L2-resident) now loaded DIRECTLY
//     from global into registers 2 K-steps ahead (no LDS round-trip; barrier
//     only protects the 2KB W-tile). kprep merged into kstats1 (block-role
//     dispatch) so prep overlaps the BW-bound A read. 4 kernels.
// ---------------------------------------------------------------------------

typedef __attribute__((ext_vector_type(8))) short  s16x8;
typedef __attribute__((ext_vector_type(4))) float  f32x4;
typedef unsigned short u16;
typedef unsigned int   u32;
typedef unsigned long long u64;

#define LOG2E 1.4426950408889634f
#define NB 4
#define NN 2048
#define NF 128
#define NH 256
#define NC 64
#define KS 64
#define NK (NN / KS)

__device__ __forceinline__ u16 f2bf(float f) {
    u32 x = __builtin_bit_cast(u32, f);
    return (u16)((x + 0x7fffu + ((x >> 16) & 1u)) >> 16);
}

// ---- kpre: block-role dispatch -------------------------------------------
// bids [0,256): X-tile prep (transpose + layer1 dots), 32 rows each.
// bids [256,260): weight transposes (W1T, W2T).
// bids [260, 260+8192): stats rows (deg -> dvec, adjacency bitmask).
__global__ void kpre(const float* __restrict__ X, const float* __restrict__ A,
                     const float* __restrict__ a1s, const float* __restrict__ a1d,
                     const float* __restrict__ W1, const float* __restrict__ W2,
                     u16* __restrict__ XT, u16* __restrict__ W1T,
                     u16* __restrict__ W2T, float* __restrict__ FS1,
                     float* __restrict__ FD1, float* __restrict__ dvec,
                     u64* __restrict__ bm) {
    __shared__ float tile[32][132];
    __shared__ float asb[NF], adb[NF];
    __shared__ float dred[32][8][2];
    const int bid = blockIdx.x;
    const int t = threadIdx.x;
    if (bid >= NB * 64 + 4) {               // ---- stats role ----
        int row = bid - (NB * 64 + 4);      // 0..8191
        const float* Arow = A + (size_t)row * NN;
        int l = t & 63, wv = t >> 6;
        float deg = 0.f;
#pragma unroll
        for (int e = 0; e < 8; e++) {
            int j = e * 256 + t;
            float a = Arow[j];
            deg += a;
            u64 m = __ballot(a > 0.f);
            if (l == 0) bm[(size_t)row * 32 + e * 4 + wv] = m;
        }
#pragma unroll
        for (int o = 32; o > 0; o >>= 1) deg += __shfl_down(deg, o);
        if (l == 0) dred[0][wv][0] = deg;
        __syncthreads();
        if (t == 0)
            dvec[row] = rsqrtf(dred[0][0][0] + dred[0][1][0] +
                               dred[0][2][0] + dred[0][3][0] + 1.0f);
        return;
    }
    if (bid >= NB * 64) {                   // ---- weight role ----
        int tt = (bid - NB * 64) * 256 + t;
        for (int i = tt; i < NF * NH; i += 1024) {
            int k = i >> 8, c = i & 255;
            W1T[c * NF + k] = f2bf(W1[i]);
        }
        for (int i = tt; i < NH * NC; i += 1024) {
            int k = i >> 6, c = i & 63;
            W2T[c * NH + k] = f2bf(W2[i]);
        }
        return;
    }
    // ---- X-tile role: b = bid>>6, 32 rows ----
    const int b = bid >> 6, i0 = (bid & 63) * 32;
    if (t < 128) asb[t] = a1s[t];
    else         adb[t - 128] = a1d[t - 128];
    for (int idx = t; idx < 32 * NF; idx += 256) {
        int r = idx >> 7, c = idx & 127;
        tile[r][c] = X[((size_t)b * NN + i0 + r) * NF + c];
    }
    __syncthreads();
    {   // layer1 dots: 32 rows x 8 chunks of 16
        int r = t >> 3, ch = t & 7;
        float ps = 0.f, pd = 0.f;
#pragma unroll
        for (int q = 0; q < 16; q++) {
            float x = tile[r][ch * 16 + q];
            ps += x * asb[ch * 16 + q];
            pd += x * adb[ch * 16 + q];
        }
        dred[r][ch][0] = ps; dred[r][ch][1] = pd;
    }
    {   // XT transpose: c = t>>1, half rows
        int c = t >> 1, half = t & 1;
        __attribute__((aligned(16))) u16 tmp[16];
#pragma unroll
        for (int q = 0; q < 16; q++) tmp[q] = f2bf(tile[half * 16 + q][c]);
        int4* dst = (int4*)&XT[((size_t)b * NF + c) * NN + i0 + half * 16];
        const int4* sv = (const int4*)tmp;
        dst[0] = sv[0]; dst[1] = sv[1];
    }
    __syncthreads();
    if (t < 64) {
        int r = t & 31, which = t >> 5;
        float s = 0.f;
#pragma unroll
        for (int ch = 0; ch < 8; ch++) s += dred[r][ch][which];
        if (which == 0) FS1[(b << 11) + i0 + r] = s * LOG2E;
        else            FD1[(b << 11) + i0 + r] = s * LOG2E;
    }
}

// ---- fused layer1: out1(LDS) = relu(rsc*(W@X)@W1+b1); FS2/FD2; OW2T --------
__global__ __launch_bounds__(512) void kspmm1(
    const u32* __restrict__ bm32, const float* __restrict__ FS,
    const float* __restrict__ FD, const float* __restrict__ dvec,
    const u16* __restrict__ XT, const u16* __restrict__ W1T,
    const u16* __restrict__ W2T, const float* __restrict__ b1,
    const float* __restrict__ a2s, const float* __restrict__ a2d,
    float* __restrict__ FS2, float* __restrict__ FD2,
    u16* __restrict__ OW2T) {
    const int b = blockIdx.y;
    const int i0 = blockIdx.x * 32;
    const int t = threadIdx.x;
    const int l = t & 63, wv = t >> 6;
    const int g = l >> 4, li = l & 15;
    const int kf = wv >> 2;          // k-half within step
    const int cf = wv & 3;           // 32-col group of X features

    __shared__ __attribute__((aligned(16))) u16 wb[2][32][64];      // 8 KB
    __shared__ __attribute__((aligned(16))) char usm[37376];        // o1|dred
    float* o1   = (float*)usm;                   // [32][260]
    float* dredp = (float*)(usm + 33280);        // [32][16][2]
    __shared__ __attribute__((aligned(16))) float tlds[32][132];
    __shared__ float rsred[16][32];
    __shared__ float rscl[32];

    const int wr = t & 31;                 // weight row
    const int wc = (t >> 5) * 4;           // 4 weight cols

    const int grow = i0 + wr;
    const float fs_r = FS[(b << 11) + grow];
    const float* FDb = FD + (b << 11);
    const float* Db  = dvec + (b << 11);
    const u32* bmrow = bm32 + ((size_t)((b << 11) + grow)) * 64;
    const u16* XTb = XT + (size_t)b * NF * NN;
    const u16* bbase = XTb + (size_t)(cf * 32 + li) * NN + kf * 32 + g * 8;

    float rs_acc = 0.f;

#define LOADW1(K0_, FDV, DJV, WBI, JJ) { \
    FDV = *(const float4*)&FDb[(K0_) + wc]; \
    DJV = *(const float4*)&Db[(K0_) + wc]; \
    WBI = bmrow[((K0_) + wc) >> 5] >> (wc & 31); \
    JJ = (K0_) + wc; }

#define WRITEW1(BI_, FDV, DJV, WBI, JJ) { \
    float fdq[4] = {FDV.x, FDV.y, FDV.z, FDV.w}; \
    float djq[4] = {DJV.x, DJV.y, DJV.z, DJV.w}; \
    u16 wq[4]; \
    _Pragma("unroll") \
    for (int q = 0; q < 4; q++) { \
        float s_ = fs_r + fdq[q]; \
        float e_ = exp2f(fmaxf(s_, 0.2f * s_)); \
        rs_acc += ((WBI >> q) & 1u) ? e_ : 0.f; \
        float w_ = e_ * djq[q]; \
        if (JJ + q == grow) w_ *= 2.f; \
        wq[q] = ((WBI >> q) & 1u) ? f2bf(w_) : (u16)0; } \
    uint2 pk; \
    pk.x = (u32)wq[0] | ((u32)wq[1] << 16); \
    pk.y = (u32)wq[2] | ((u32)wq[3] << 16); \
    *(uint2*)&wb[BI_][wr][wc ^ ((wr & 7) << 3)] = pk; }

#define BLOAD1(K0_, R0, R1) { \
    const u16* bp = bbase + (size_t)(K0_) * KS; \
    R0 = *(const s16x8*)bp; \
    R1 = *(const s16x8*)(bp + (size_t)16 * NN); }

#define MSTEP1(BI_, B0, B1) { \
    const int kc = kf * 32 + g * 8; \
    const int swr = (li & 7) << 3; \
    s16x8 af0 = *(const s16x8*)&wb[BI_][li]     [kc ^ swr]; \
    s16x8 af1 = *(const s16x8*)&wb[BI_][16 + li][kc ^ swr]; \
    acc00 = __builtin_amdgcn_mfma_f32_16x16x32_bf16(af0, B0, acc00, 0, 0, 0); \
    acc01 = __builtin_amdgcn_mfma_f32_16x16x32_bf16(af0, B1, acc01, 0, 0, 0); \
    acc10 = __builtin_amdgcn_mfma_f32_16x16x32_bf16(af1, B0, acc10, 0, 0, 0); \
    acc11 = __builtin_amdgcn_mfma_f32_16x16x32_bf16(af1, B1, acc11, 0, 0, 0); }

    f32x4 zero = {0.f, 0.f, 0.f, 0.f};
    f32x4 acc00 = zero, acc01 = zero, acc10 = zero, acc11 = zero;
    s16x8 bA0, bA1, bB0, bB1;
    float4 fdvA, djvA, fdvB, djvB; u32 wbA, wbB; int jjA, jjB;

    LOADW1(0, fdvA, djvA, wbA, jjA);
    BLOAD1(0, bA0, bA1);
    LOADW1(KS, fdvB, djvB, wbB, jjB);
    BLOAD1(1, bB0, bB1);
    WRITEW1(0, fdvA, djvA, wbA, jjA);

#pragma unroll 1
    for (int kk = 0; kk < NK; kk += 2) {
        __syncthreads();
        MSTEP1(0, bA0, bA1);
        WRITEW1(1, fdvB, djvB, wbB, jjB);
        if (kk + 2 < NK) { LOADW1((kk + 2) * KS, fdvA, djvA, wbA, jjA);
                           BLOAD1(kk + 2, bA0, bA1); }
        __syncthreads();
        MSTEP1(1, bB0, bB1);
        if (kk + 2 < NK) WRITEW1(0, fdvA, djvA, wbA, jjA);
        if (kk + 3 < NK) { LOADW1((kk + 3) * KS, fdvB, djvB, wbB, jjB);
                           BLOAD1(kk + 3, bB0, bB1); }
    }
    rsred[t >> 5][wr] = rs_acc;
    __syncthreads();
    if (t < 32) {               // rowscale1 = d_i / rs_i
        float rs = 0.f;
#pragma unroll
        for (int s = 0; s < 16; ++s) rs += rsred[s][t];
        rscl[t] = Db[i0 + t] / rs;
    }
    // combine k-halves into tlds (f32)
    if (wv < 4) {
#pragma unroll
        for (int r = 0; r < 4; r++) {
            tlds[g * 4 + r]     [cf * 32 + li]      = acc00[r];
            tlds[g * 4 + r]     [cf * 32 + 16 + li] = acc01[r];
            tlds[16 + g * 4 + r][cf * 32 + li]      = acc10[r];
            tlds[16 + g * 4 + r][cf * 32 + 16 + li] = acc11[r];
        }
    }
    __syncthreads();
    if (wv >= 4) {
#pragma unroll
        for (int r = 0; r < 4; r++) {
            tlds[g * 4 + r]     [cf * 32 + li]      += acc00[r];
            tlds[g * 4 + r]     [cf * 32 + 16 + li] += acc01[r];
            tlds[16 + g * 4 + r][cf * 32 + li]      += acc10[r];
            tlds[16 + g * 4 + r][cf * 32 + 16 + li] += acc11[r];
        }
    }
    __syncthreads();
    // stage 2: out1_block[32][256] = T[32][128] @ W1[128][256]; wave = 32 cols
    const int c0 = wv * 32;
    f32x4 p00 = zero, p01 = zero, p10 = zero, p11 = zero;
    for (int k2 = 0; k2 < 4; ++k2) {
        s16x8 a2f[2];
#pragma unroll
        for (int mt = 0; mt < 2; ++mt) {
            const float* tp = &tlds[mt * 16 + li][k2 * 32 + g * 8];
            float4 t0 = *(const float4*)tp;
            float4 t1 = *(const float4*)(tp + 4);
            s16x8 aa;
            aa[0] = (short)f2bf(t0.x); aa[1] = (short)f2bf(t0.y);
            aa[2] = (short)f2bf(t0.z); aa[3] = (short)f2bf(t0.w);
            aa[4] = (short)f2bf(t1.x); aa[5] = (short)f2bf(t1.y);
            aa[6] = (short)f2bf(t1.z); aa[7] = (short)f2bf(t1.w);
            a2f[mt] = aa;
        }
        s16x8 w0 = *(const s16x8*)&W1T[(size_t)(c0 + li) * NF + k2 * 32 + g * 8];
        s16x8 w1 = *(const s16x8*)&W1T[(size_t)(c0 + 16 + li) * NF + k2 * 32 + g * 8];
        p00 = __builtin_amdgcn_mfma_f32_16x16x32_bf16(a2f[0], w0, p00, 0, 0, 0);
        p01 = __builtin_amdgcn_mfma_f32_16x16x32_bf16(a2f[0], w1, p01, 0, 0, 0);
        p10 = __builtin_amdgcn_mfma_f32_16x16x32_bf16(a2f[1], w0, p10, 0, 0, 0);
        p11 = __builtin_amdgcn_mfma_f32_16x16x32_bf16(a2f[1], w1, p11, 0, 0, 0);
    }
    __syncthreads();   // main-loop LDS dead; rscl visible; o1 region free
    // out1 block -> LDS o1[32][260] with relu(scale+bias)
#pragma unroll
    for (int mt = 0; mt < 2; ++mt) {
        f32x4 pa = mt ? p10 : p00;
        f32x4 pb = mt ? p11 : p01;
#pragma unroll
        for (int r = 0; r < 4; r++) {
            int rr = mt * 16 + g * 4 + r;
            float rsc = rscl[rr];
            int ca = c0 + li, cb2 = c0 + 16 + li;
            o1[rr * 260 + ca]  = fmaxf(pa[r] * rsc + b1[ca], 0.f);
            o1[rr * 260 + cb2] = fmaxf(pb[r] * rsc + b1[cb2], 0.f);
        }
    }
    __syncthreads();
    // layer-2 dots: 32 rows x 16 segs of 16 cols
    {
        int r = t >> 4, seg = t & 15;
        float ps = 0.f, pd = 0.f;
#pragma unroll
        for (int q = 0; q < 4; q++) {
            float4 xv = *(const float4*)&o1[r * 260 + seg * 16 + q * 4];
            float4 sv = *(const float4*)&a2s[seg * 16 + q * 4];
            float4 dv = *(const float4*)&a2d[seg * 16 + q * 4];
            ps += xv.x * sv.x + xv.y * sv.y + xv.z * sv.z + xv.w * sv.w;
            pd += xv.x * dv.x + xv.y * dv.y + xv.z * dv.z + xv.w * dv.w;
        }
        dredp[(r * 16 + seg) * 2]     = ps;
        dredp[(r * 16 + seg) * 2 + 1] = pd;
    }
    // OW2 = out1_block @ W2 : wave (mt = wv&1, nt = wv>>1), 8 k-steps
    {
        const int mt = wv & 1, nt = wv >> 1;
        f32x4 acc = zero;
        for (int k2 = 0; k2 < 8; ++k2) {
            int kc = k2 * 32 + g * 8;
            const float* op = &o1[(mt * 16 + li) * 260 + kc];
            float4 v0 = *(const float4*)op;
            float4 v1 = *(const float4*)(op + 4);
            s16x8 aa;
            aa[0] = (short)f2bf(v0.x); aa[1] = (short)f2bf(v0.y);
            aa[2] = (short)f2bf(v0.z); aa[3] = (short)f2bf(v0.w);
            aa[4] = (short)f2bf(v1.x); aa[5] = (short)f2bf(v1.y);
            aa[6] = (short)f2bf(v1.z); aa[7] = (short)f2bf(v1.w);
            s16x8 bb = *(const s16x8*)&W2T[(size_t)(nt * 16 + li) * NH + kc];
            acc = __builtin_amdgcn_mfma_f32_16x16x32_bf16(aa, bb, acc, 0, 0, 0);
        }
        int c = nt * 16 + li;
        uint2 pk;
        pk.x = (u32)f2bf(acc[0]) | ((u32)f2bf(acc[1]) << 16);
        pk.y = (u32)f2bf(acc[2]) | ((u32)f2bf(acc[3]) << 16);
        *(uint2*)&OW2T[((size_t)b * NC + c) * NN + i0 + mt * 16 + g * 4] = pk;
    }
    __syncthreads();
    if (t < 64) {              // reduce dots partials -> FS2/FD2
        int r = t & 31, which = t >> 5;
        float s = 0.f;
#pragma unroll
        for (int seg = 0; seg < 16; ++seg) s += dredp[(r * 16 + seg) * 2 + which];
        if (which == 0) FS2[(b << 11) + i0 + r] = s * LOG2E;
        else            FD2[(b << 11) + i0 + r] = s * LOG2E;
    }
#undef LOADW1
#undef WRITEW1
#undef BLOAD1
#undef MSTEP1
}

// ---- layer2 spmm: node = rsc2 * W2mat @ OW2 + b2; graph partials -----------
__global__ __launch_bounds__(512) void kspmm2(
    const u32* __restrict__ bm32, const float* __restrict__ FS,
    const float* __restrict__ FD, const float* __restrict__ dvec,
    const u16* __restrict__ OW2T, const float* __restrict__ b2,
    float* __restrict__ node, float* __restrict__ gpart) {
    const int b = blockIdx.y;
    const int i0 = blockIdx.x * 32;
    const int t = threadIdx.x;
    const int l = t & 63, wv = t >> 6;
    const int g = l >> 4, li = l & 15;
    const int kf = wv >> 2;
    const int cf = wv & 3;

    __shared__ __attribute__((aligned(16))) u16 wb2[2][32][64];
    __shared__ __attribute__((aligned(16))) float tl2[32][68];
    __shared__ float rsred[16][32];
    __shared__ float rscl[32];

    const int wr = t & 31;
    const int wc = (t >> 5) * 4;

    const int grow = i0 + wr;
    const float fs_r = FS[(b << 11) + grow];
    const float* FDb = FD + (b << 11);
    const float* Db  = dvec + (b << 11);
    const u32* bmrow = bm32 + ((size_t)((b << 11) + grow)) * 64;
    const u16* Ob = OW2T + (size_t)b * NC * NN;
    const u16* bbase = Ob + (size_t)(cf * 16 + li) * NN + kf * 32 + g * 8;

    float rs_acc = 0.f;

#define LOADW2(K0_, FDV, DJV, WBI, JJ) { \
    FDV = *(const float4*)&FDb[(K0_) + wc]; \
    DJV = *(const float4*)&Db[(K0_) + wc]; \
    WBI = bmrow[((K0_) + wc) >> 5] >> (wc & 31); \
    JJ = (K0_) + wc; }

#define WRITEW2(BI_, FDV, DJV, WBI, JJ) { \
    float fdq[4] = {FDV.x, FDV.y, FDV.z, FDV.w}; \
    float djq[4] = {DJV.x, DJV.y, DJV.z, DJV.w}; \
    u16 wq[4]; \
    _Pragma("unroll") \
    for (int q = 0; q < 4; q++) { \
        float s_ = fs_r + fdq[q]; \
        float e_ = exp2f(fmaxf(s_, 0.2f * s_)); \
        rs_acc += ((WBI >> q) & 1u) ? e_ : 0.f; \
        float w_ = e_ * djq[q]; \
        if (JJ + q == grow) w_ *= 2.f; \
        wq[q] = ((WBI >> q) & 1u) ? f2bf(w_) : (u16)0; } \
    uint2 pk; \
    pk.x = (u32)wq[0] | ((u32)wq[1] << 16); \
    pk.y = (u32)wq[2] | ((u32)wq[3] << 16); \
    *(uint2*)&wb2[BI_][wr][wc ^ ((wr & 7) << 3)] = pk; }

#define BLOAD2(K0_, R0) { \
    R0 = *(const s16x8*)(bbase + (size_t)(K0_) * KS); }

#define MSTEP2(BI_, B0) { \
    const int kc = kf * 32 + g * 8; \
    const int swr = (li & 7) << 3; \
    s16x8 af0 = *(const s16x8*)&wb2[BI_][li]     [kc ^ swr]; \
    s16x8 af1 = *(const s16x8*)&wb2[BI_][16 + li][kc ^ swr]; \
    acc0 = __builtin_amdgcn_mfma_f32_16x16x32_bf16(af0, B0, acc0, 0, 0, 0); \
    acc1 = __builtin_amdgcn_mfma_f32_16x16x32_bf16(af1, B0, acc1, 0, 0, 0); }

    f32x4 zero = {0.f, 0.f, 0.f, 0.f};
    f32x4 acc0 = zero, acc1 = zero;
    s16x8 bA, bB;
    float4 fdvA, djvA, fdvB, djvB; u32 wbA, wbB; int jjA, jjB;

    LOADW2(0, fdvA, djvA, wbA, jjA);
    BLOAD2(0, bA);
    LOADW2(KS, fdvB, djvB, wbB, jjB);
    BLOAD2(1, bB);
    WRITEW2(0, fdvA, djvA, wbA, jjA);

#pragma unroll 1
    for (int kk = 0; kk < NK; kk += 2) {
        __syncthreads();
        MSTEP2(0, bA);
        WRITEW2(1, fdvB, djvB, wbB, jjB);
        if (kk + 2 < NK) { LOADW2((kk + 2) * KS, fdvA, djvA, wbA, jjA);
                           BLOAD2(kk + 2, bA); }
        __syncthreads();
        MSTEP2(1, bB);
        if (kk + 2 < NK) WRITEW2(0, fdvA, djvA, wbA, jjA);
        if (kk + 3 < NK) { LOADW2((kk + 3) * KS, fdvB, djvB, wbB, jjB);
                           BLOAD2(kk + 3, bB); }
    }
    rsred[t >> 5][wr] = rs_acc;
    __syncthreads();
    if (t < 32) {
        float rs = 0.f;
#pragma unroll
        for (int s = 0; s < 16; ++s) rs += rsred[s][t];
        rscl[t] = Db[i0 + t] / rs;
    }
    if (wv < 4) {
#pragma unroll
        for (int r = 0; r < 4; r++) {
            tl2[g * 4 + r]     [cf * 16 + li] = acc0[r];
            tl2[16 + g * 4 + r][cf * 16 + li] = acc1[r];
        }
    }
    __syncthreads();
    if (wv >= 4) {
#pragma unroll
        for (int r = 0; r < 4; r++) {
            tl2[g * 4 + r]     [cf * 16 + li] += acc0[r];
            tl2[16 + g * 4 + r][cf * 16 + li] += acc1[r];
        }
    }
    __syncthreads();
    {   // scale + bias, store node, write back for graph partial
        int r = t >> 4, c0 = (t & 15) * 4;
        float rsc = rscl[r];
        float4 v = *(const float4*)&tl2[r][c0];
        float4 bb = *(const float4*)&b2[c0];
        v.x = v.x * rsc + bb.x; v.y = v.y * rsc + bb.y;
        v.z = v.z * rsc + bb.z; v.w = v.w * rsc + bb.w;
        *(float4*)&node[((size_t)(b << 11) + i0 + r) * NC + c0] = v;
        *(float4*)&tl2[r][c0] = v;
    }
    __syncthreads();
    if (t < NC) {
        float s = 0.f;
#pragma unroll
        for (int r = 0; r < 32; ++r) s += tl2[r][t];
        gpart[(((size_t)b * (NN / 32)) + blockIdx.x) * NC + t] = s;
    }
#undef LOADW2
#undef WRITEW2
#undef BLOAD2
#undef MSTEP2
}

// ---- graph scores: reduce per-block partials -------------------------------
__global__ void kgraph2(const float* __restrict__ gpart, float* __restrict__ graph) {
    int b = blockIdx.x;
    int c = threadIdx.x & 63, ch = threadIdx.x >> 6;
    float s = 0.f;
    for (int p = ch; p < NN / 32; p += 4)
        s += gpart[(((size_t)b * (NN / 32)) + p) * NC + c];
    __shared__ float red[4][64];
    red[ch][c] = s;
    __syncthreads();
    if (ch == 0) graph[b * NC + c] = red[0][c] + red[1][c] + red[2][c] + red[3][c];
}

extern "C" void kernel_launch(void* const* d_in, const int* in_sizes, int n_in,
                              void* d_out, int out_size, void* d_ws, size_t ws_size,
                              hipStream_t stream) {
    const float* X   = (const float*)d_in[0];
    const float* A   = (const float*)d_in[1];
    const float* a1s = (const float*)d_in[2];
    const float* a1d = (const float*)d_in[3];
    const float* W1  = (const float*)d_in[4];
    const float* b1  = (const float*)d_in[5];
    const float* a2s = (const float*)d_in[6];
    const float* a2d = (const float*)d_in[7];
    const float* W2  = (const float*)d_in[8];
    const float* b2  = (const float*)d_in[9];

    float* node  = (float*)d_out;                 // [4][2048][64]
    float* graph = node + (size_t)NB * NN * NC;   // [4][64]

    char* w = (char*)d_ws;
    float* FS1  = (float*)w; w += NB * NN * 4;
    float* FD1  = (float*)w; w += NB * NN * 4;
    float* FS2  = (float*)w; w += NB * NN * 4;
    float* FD2  = (float*)w; w += NB * NN * 4;
    float* dvec = (float*)w; w += NB * NN * 4;
    u64*  bm    = (u64*)w;  w += (size_t)NB * NN * 32 * 8;    // 2 MB
    u16*  XT    = (u16*)w;  w += (size_t)NB * NF * NN * 2;    // 2 MB
    u16*  OW2T  = (u16*)w;  w += (size_t)NB * NC * NN * 2;    // 1 MB
    u16*  W1T   = (u16*)w;  w += NH * NF * 2;
    u16*  W2T   = (u16*)w;  w += NC * NH * 2;
    float* gpart = (float*)w; w += (size_t)NB * (NN / 32) * NC * 4;  // 64 KB

    kpre    <<<NB * 64 + 4 + NB * NN, 256, 0, stream>>>(X, A, a1s, a1d, W1, W2,
                                                        XT, W1T, W2T, FS1, FD1,
                                                        dvec, bm);
    kspmm1  <<<dim3(NN / 32, NB), 512, 0, stream>>>((const u32*)bm, FS1, FD1, dvec,
                                                    XT, W1T, W2T, b1, a2s, a2d,
                                                    FS2, FD2, OW2T);
    kspmm2  <<<dim3(NN / 32, NB), 512, 0, stream>>>((const u32*)bm, FS2, FD2, dvec,
                                                    OW2T, b2, node, gpart);
    kgraph2 <<<NB, 256, 0, stream>>>(gpart, graph);
}

// Round 6
// 108.272 us; speedup vs baseline: 1.0020x; 1.0020x over previous
//
#include <hip/hip_runtime.h>

// ---------------------------------------------------------------------------
// TwoLayerGCN on MI355X (gfx950).  B=4, N=2048, F=128, H=256, C=64.
//
//   d_i = rsqrt(nnz_i + 1) ; w_ij = [A_ij>0] exp(lrelu(fs_i+fd_j)) d_j (1+[i==j])
//   rs_i = sum_j [A_ij>0] exp(lrelu(fs_i+fd_j))
//   layer1: out1 = relu( (d_i/rs_i)(W@X)@W1 + b1 )
//   layer2: node = (d_i/rs_i) W2mat@(out1@W2) + b2 ; graph = sum_i node
//
// R5: dense-MFMA SpMM was barrier/latency-bound (45us, MfmaUtil 4%: vmcnt(0)
// drain at every barrier kills prefetch; 1 block/CU). A is ~9.75% dense ->
// ROW-GATHER SpMM: kpre emits CSR (ballot+mbcnt) during the one 64MB A read;
// kgat1/kgat2 gather rows with NO barriers in the hot loop (w computed
// wave-parallel per 64-chunk, inner loop = coalesced bf16 row load + FMA).
// Dense T@W1 / out1@W2 stay as small fused MFMA epilogues per 8-row block.
// ---------------------------------------------------------------------------

typedef __attribute__((ext_vector_type(8))) short  s16x8;
typedef __attribute__((ext_vector_type(4))) float  f32x4;
typedef unsigned short u16;
typedef unsigned int   u32;
typedef unsigned long long u64;

#define LOG2E 1.4426950408889634f
#define NB 4
#define NN 2048
#define NF 128
#define NH 256
#define NC 64
#define CST 320            // CSR row stride in u16 (max deg ~260)

__device__ __forceinline__ u16 f2bf(float f) {
    u32 x = __builtin_bit_cast(u32, f);
    return (u16)((x + 0x7fffu + ((x >> 16) & 1u)) >> 16);
}
__device__ __forceinline__ float bflo(u32 x) {
    return __builtin_bit_cast(float, x << 16);
}
__device__ __forceinline__ float bfhi(u32 x) {
    return __builtin_bit_cast(float, x & 0xffff0000u);
}
__device__ __forceinline__ u32 mbcnt64(u64 m) {
    return __builtin_amdgcn_mbcnt_hi((u32)(m >> 32),
           __builtin_amdgcn_mbcnt_lo((u32)m, 0));
}

// ---- kpre: block-role dispatch ---------------------------------------------
// [0,256): X rows -> Xbf (bf16 row-major) + layer1 dots FS1/FD1.
// [256,260): W1T/W2T transposes.
// [260,260+8192): stats row: A read -> CSR idx + cnt + dvec.
__global__ void kpre(const float* __restrict__ X, const float* __restrict__ A,
                     const float* __restrict__ a1s, const float* __restrict__ a1d,
                     const float* __restrict__ W1, const float* __restrict__ W2,
                     u16* __restrict__ Xbf, u16* __restrict__ W1T,
                     u16* __restrict__ W2T, float* __restrict__ FS1,
                     float* __restrict__ FD1, float* __restrict__ dvec,
                     int* __restrict__ cnt, u16* __restrict__ idx) {
    const int bid = blockIdx.x;
    const int t = threadIdx.x;
    if (bid >= NB * 64 + 4) {                 // ---- stats role ----
        __shared__ u64 masks[32];
        __shared__ u32 basep[33];
        int row = bid - (NB * 64 + 4);        // 0..8191
        const float* Arow = A + (size_t)row * NN;
        int l = t & 63, wv = t >> 6;
#pragma unroll
        for (int e = 0; e < 8; e++) {
            float a = Arow[e * 256 + t];
            u64 m = __ballot(a > 0.f);
            if (l == 0) masks[e * 4 + wv] = m;
        }
        __syncthreads();
        if (t == 0) {
            u32 s = 0;
#pragma unroll
            for (int m = 0; m < 32; m++) { basep[m] = s; s += __popcll(masks[m]); }
            basep[32] = s;
            cnt[row] = (int)s;
            dvec[row] = rsqrtf((float)s + 1.0f);
        }
        __syncthreads();
#pragma unroll
        for (int s = 0; s < 8; s++) {
            int mi = wv * 8 + s;
            u64 m = masks[mi];
            if ((m >> l) & 1ull)
                idx[(size_t)row * CST + basep[mi] + mbcnt64(m)] = (u16)(mi * 64 + l);
        }
        return;
    }
    if (bid >= NB * 64) {                     // ---- weight role ----
        int tt = (bid - NB * 64) * 256 + t;
        for (int i = tt; i < NF * NH; i += 1024) {
            int k = i >> 8, c = i & 255;
            W1T[c * NF + k] = f2bf(W1[i]);
        }
        for (int i = tt; i < NH * NC; i += 1024) {
            int k = i >> 6, c = i & 63;
            W2T[c * NH + k] = f2bf(W2[i]);
        }
        return;
    }
    // ---- X role: 32 rows ----
    __shared__ float tile[32][132];
    __shared__ float asb[NF], adb[NF];
    __shared__ float dred[32][8][2];
    const int b = bid >> 6, i0 = (bid & 63) * 32;
    if (t < 128) asb[t] = a1s[t];
    else         adb[t - 128] = a1d[t - 128];
    for (int i = t; i < 32 * NF; i += 256) {
        int r = i >> 7, c = i & 127;
        tile[r][c] = X[((size_t)b * NN + i0 + r) * NF + c];
    }
    __syncthreads();
    {   // layer1 dots
        int r = t >> 3, ch = t & 7;
        float ps = 0.f, pd = 0.f;
#pragma unroll
        for (int q = 0; q < 16; q++) {
            float x = tile[r][ch * 16 + q];
            ps += x * asb[ch * 16 + q];
            pd += x * adb[ch * 16 + q];
        }
        dred[r][ch][0] = ps; dred[r][ch][1] = pd;
    }
    {   // Xbf row-major bf16
        int r = t >> 3, c = (t & 7) * 16;
        __attribute__((aligned(16))) u16 tmp[16];
#pragma unroll
        for (int q = 0; q < 16; q++) tmp[q] = f2bf(tile[r][c + q]);
        int4* dst = (int4*)&Xbf[((size_t)b * NN + i0 + r) * NF + c];
        const int4* sv = (const int4*)tmp;
        dst[0] = sv[0]; dst[1] = sv[1];
    }
    __syncthreads();
    if (t < 64) {
        int r = t & 31, which = t >> 5;
        float s = 0.f;
#pragma unroll
        for (int ch = 0; ch < 8; ch++) s += dred[r][ch][which];
        if (which == 0) FS1[(b << 11) + i0 + r] = s * LOG2E;
        else            FD1[(b << 11) + i0 + r] = s * LOG2E;
    }
}

// ---- kgat1: gather layer1 + fused T@W1, dots2, out1@W2 ---------------------
// 8 waves x 1 row each; gather X rows (bf16, 4 feats/lane over half-waves,
// 2 nbrs/iter); epilogue: T'(rsc-scaled bf16) @ W1 -> o1(f32,relu+b1) ->
// {dots2 (waves 4-7) || o1@W2 -> OW2row (waves 0-3)}.
__global__ __launch_bounds__(512) void kgat1(
    const u16* __restrict__ idx, const int* __restrict__ cnt,
    const float* __restrict__ FS, const float* __restrict__ FD,
    const float* __restrict__ dvec, const u16* __restrict__ Xbf,
    const u16* __restrict__ W1T, const u16* __restrict__ W2T,
    const float* __restrict__ b1, const float* __restrict__ a2s,
    const float* __restrict__ a2d, float* __restrict__ FS2,
    float* __restrict__ FD2, u16* __restrict__ OW2row) {
    const int b = blockIdx.y;
    const int i0 = blockIdx.x * 8;
    const int t = threadIdx.x, wv = t >> 6, l = t & 63;
    const int g = l >> 4, li = l & 15;
    const int h = l >> 5, hl = l & 31;

    __shared__ uint2 wlds[8][64];
    __shared__ __attribute__((aligned(16))) u16 tlds[16][136];
    __shared__ __attribute__((aligned(16))) float o1[16][264];

    for (int z = t; z < 8 * 136; z += 512)     // zero pad rows 8..15 of T'
        ((u16*)tlds)[8 * 136 + z] = 0;

    const int row = i0 + wv;
    const int grow = (b << 11) + row;
    const float fs = FS[grow];
    const float* FDb = FD + (b << 11);
    const float* Db  = dvec + (b << 11);
    const u16* irow = idx + (size_t)grow * CST;
    const int cn = cnt[grow];
    const char* Xb = (const char*)(Xbf + (size_t)b * NN * NF);

    f32x4 acc = {0.f, 0.f, 0.f, 0.f};
    float rs = 0.f;
    for (int p0 = 0; p0 < cn; p0 += 64) {
        int p = min(p0 + l, cn - 1);
        int j = irow[p];
        float fd = FDb[j], dj = Db[j];
        float s = fs + fd;
        float e = exp2f(fmaxf(s, 0.2f * s));
        e = (p0 + l < cn) ? e : 0.f;
        rs += e;
        float w = e * dj * ((j == row) ? 2.f : 1.f);
        wlds[wv][l] = (uint2){__builtin_bit_cast(u32, w), (u32)j * (NF * 2)};
        int nq = min(64, cn - p0);
#pragma unroll 2
        for (int q = 0; q < nq; q += 2) {
            uint2 wj = wlds[wv][q + h];
            float w_ = __builtin_bit_cast(float, wj.x);
            uint2 xv = *(const uint2*)(Xb + wj.y + hl * 8);
            acc[0] += w_ * bflo(xv.x);
            acc[1] += w_ * bfhi(xv.x);
            acc[2] += w_ * bflo(xv.y);
            acc[3] += w_ * bfhi(xv.y);
        }
    }
#pragma unroll
    for (int r = 0; r < 4; r++) acc[r] += __shfl_xor(acc[r], 32);
#pragma unroll
    for (int o = 1; o < 64; o <<= 1) rs += __shfl_xor(rs, o);
    float rsc = Db[row] / fmaxf(rs, 1e-30f);
    if (h == 0) {      // T' row: feats hl*4..+3, rsc pre-applied
        uint2 pk;
        pk.x = (u32)f2bf(acc[0] * rsc) | ((u32)f2bf(acc[1] * rsc) << 16);
        pk.y = (u32)f2bf(acc[2] * rsc) | ((u32)f2bf(acc[3] * rsc) << 16);
        *(uint2*)&tlds[wv][hl * 4] = pk;
    }
    __syncthreads();
    // GEMM1: o1[8][256] = T'[8pad16][128] @ W1 ; wave = 32 cols
    f32x4 zero = {0.f, 0.f, 0.f, 0.f};
    f32x4 p0a = zero, p1a = zero;
#pragma unroll
    for (int k2 = 0; k2 < 4; k2++) {
        s16x8 af = *(const s16x8*)&tlds[li][k2 * 32 + g * 8];
        s16x8 w0 = *(const s16x8*)&W1T[(size_t)(wv * 32 + li) * NF + k2 * 32 + g * 8];
        s16x8 w1 = *(const s16x8*)&W1T[(size_t)(wv * 32 + 16 + li) * NF + k2 * 32 + g * 8];
        p0a = __builtin_amdgcn_mfma_f32_16x16x32_bf16(af, w0, p0a, 0, 0, 0);
        p1a = __builtin_amdgcn_mfma_f32_16x16x32_bf16(af, w1, p1a, 0, 0, 0);
    }
#pragma unroll
    for (int r = 0; r < 4; r++) {   // rows g*4+r; g>=2 are pad rows -> 0
        int rr = g * 4 + r;
        int ca = wv * 32 + li, cb = ca + 16;
        o1[rr][ca] = (g < 2) ? fmaxf(p0a[r] + b1[ca], 0.f) : 0.f;
        o1[rr][cb] = (g < 2) ? fmaxf(p1a[r] + b1[cb], 0.f) : 0.f;
    }
    __syncthreads();
    if (wv >= 4) {     // dots2: 4 waves x 2 rows, 8 feats/lane-half
        int r = (wv - 4) * 2 + h;
        float ps = 0.f, pd = 0.f;
#pragma unroll
        for (int q = 0; q < 2; q++) {
            int c = hl * 8 + q * 4;
            float4 xv = *(const float4*)&o1[r][c];
            float4 sv = *(const float4*)&a2s[c];
            float4 dv = *(const float4*)&a2d[c];
            ps += xv.x * sv.x + xv.y * sv.y + xv.z * sv.z + xv.w * sv.w;
            pd += xv.x * dv.x + xv.y * dv.y + xv.z * dv.z + xv.w * dv.w;
        }
#pragma unroll
        for (int o = 1; o < 32; o <<= 1) {
            ps += __shfl_xor(ps, o); pd += __shfl_xor(pd, o);
        }
        if (hl == 0) {
            FS2[(b << 11) + i0 + r] = ps * LOG2E;
            FD2[(b << 11) + i0 + r] = pd * LOG2E;
        }
    } else {           // GEMM2: OW2row[8][64] = o1[8pad16][256] @ W2 ; wave = 16 cols
        f32x4 q0 = zero;
#pragma unroll
        for (int k2 = 0; k2 < 8; k2++) {
            const float* op = &o1[li][k2 * 32 + g * 8];
            float4 v0 = *(const float4*)op;
            float4 v1 = *(const float4*)(op + 4);
            s16x8 aa;
            aa[0] = (short)f2bf(v0.x); aa[1] = (short)f2bf(v0.y);
            aa[2] = (short)f2bf(v0.z); aa[3] = (short)f2bf(v0.w);
            aa[4] = (short)f2bf(v1.x); aa[5] = (short)f2bf(v1.y);
            aa[6] = (short)f2bf(v1.z); aa[7] = (short)f2bf(v1.w);
            s16x8 bb = *(const s16x8*)&W2T[(size_t)(wv * 16 + li) * NH + k2 * 32 + g * 8];
            q0 = __builtin_amdgcn_mfma_f32_16x16x32_bf16(aa, bb, q0, 0, 0, 0);
        }
        if (g < 2) {
#pragma unroll
            for (int r = 0; r < 4; r++) {
                int rr = g * 4 + r;
                OW2row[((size_t)(b << 11) + i0 + rr) * NC + wv * 16 + li] = f2bf(q0[r]);
            }
        }
    }
}

// ---- kgat2: gather layer2 on OW2 rows; node + graph partials ---------------
__global__ __launch_bounds__(512) void kgat2(
    const u16* __restrict__ idx, const int* __restrict__ cnt,
    const float* __restrict__ FS, const float* __restrict__ FD,
    const float* __restrict__ dvec, const u16* __restrict__ OW2row,
    const float* __restrict__ b2, float* __restrict__ node,
    float* __restrict__ gpart) {
    const int b = blockIdx.y;
    const int i0 = blockIdx.x * 8;
    const int t = threadIdx.x, wv = t >> 6, l = t & 63;
    const int h = l >> 5, hl = l & 31;
    __shared__ uint2 wlds[8][64];
    __shared__ float gsm[8][64];

    const int row = i0 + wv;
    const int grow = (b << 11) + row;
    const float fs = FS[grow];
    const float* FDb = FD + (b << 11);
    const float* Db  = dvec + (b << 11);
    const u16* irow = idx + (size_t)grow * CST;
    const int cn = cnt[grow];
    const char* Ob = (const char*)(OW2row + (size_t)(b << 11) * NC);

    float ax = 0.f, ay = 0.f;
    float rs = 0.f;
    for (int p0 = 0; p0 < cn; p0 += 64) {
        int p = min(p0 + l, cn - 1);
        int j = irow[p];
        float fd = FDb[j], dj = Db[j];
        float s = fs + fd;
        float e = exp2f(fmaxf(s, 0.2f * s));
        e = (p0 + l < cn) ? e : 0.f;
        rs += e;
        float w = e * dj * ((j == row) ? 2.f : 1.f);
        wlds[wv][l] = (uint2){__builtin_bit_cast(u32, w), (u32)j * (NC * 2)};
        int nq = min(64, cn - p0);
#pragma unroll 2
        for (int q = 0; q < nq; q += 2) {
            uint2 wj = wlds[wv][q + h];
            float w_ = __builtin_bit_cast(float, wj.x);
            u32 xv = *(const u32*)(Ob + wj.y + hl * 4);
            ax += w_ * bflo(xv);
            ay += w_ * bfhi(xv);
        }
    }
    ax += __shfl_xor(ax, 32);
    ay += __shfl_xor(ay, 32);
#pragma unroll
    for (int o = 1; o < 64; o <<= 1) rs += __shfl_xor(rs, o);
    float rsc = Db[row] / fmaxf(rs, 1e-30f);
    int c = hl * 2;
    float2 bb = *(const float2*)&b2[c];
    float vx = ax * rsc + bb.x, vy = ay * rsc + bb.y;
    if (h == 0) {
        float2 v2 = {vx, vy};
        *(float2*)&node[(size_t)grow * NC + c] = v2;
        *(float2*)&gsm[wv][c] = v2;
    }
    __syncthreads();
    if (t < NC) {
        float s = 0.f;
#pragma unroll
        for (int r = 0; r < 8; r++) s += gsm[r][t];
        gpart[(((size_t)b * (NN / 8)) + blockIdx.x) * NC + t] = s;
    }
}

// ---- graph scores: reduce per-block partials -------------------------------
__global__ void kgraph2(const float* __restrict__ gpart, float* __restrict__ graph) {
    int b = blockIdx.x;
    int c = threadIdx.x & 63, ch = threadIdx.x >> 6;
    float s = 0.f;
    for (int p = ch; p < NN / 8; p += 4)
        s += gpart[(((size_t)b * (NN / 8)) + p) * NC + c];
    __shared__ float red[4][64];
    red[ch][c] = s;
    __syncthreads();
    if (ch == 0) graph[b * NC + c] = red[0][c] + red[1][c] + red[2][c] + red[3][c];
}

extern "C" void kernel_launch(void* const* d_in, const int* in_sizes, int n_in,
                              void* d_out, int out_size, void* d_ws, size_t ws_size,
                              hipStream_t stream) {
    const float* X   = (const float*)d_in[0];
    const float* A   = (const float*)d_in[1];
    const float* a1s = (const float*)d_in[2];
    const float* a1d = (const float*)d_in[3];
    const float* W1  = (const float*)d_in[4];
    const float* b1  = (const float*)d_in[5];
    const float* a2s = (const float*)d_in[6];
    const float* a2d = (const float*)d_in[7];
    const float* W2  = (const float*)d_in[8];
    const float* b2  = (const float*)d_in[9];

    float* node  = (float*)d_out;                 // [4][2048][64]
    float* graph = node + (size_t)NB * NN * NC;   // [4][64]

    char* w = (char*)d_ws;
    float* FS1  = (float*)w; w += NB * NN * 4;
    float* FD1  = (float*)w; w += NB * NN * 4;
    float* FS2  = (float*)w; w += NB * NN * 4;
    float* FD2  = (float*)w; w += NB * NN * 4;
    float* dvec = (float*)w; w += NB * NN * 4;
    int*  cntv  = (int*)w;  w += NB * NN * 4;
    float* gpart = (float*)w; w += (size_t)NB * (NN / 8) * NC * 4;   // 256 KB
    u16*  Xbf   = (u16*)w;  w += (size_t)NB * NN * NF * 2;           // 2 MB
    u16*  OW2row = (u16*)w; w += (size_t)NB * NN * NC * 2;           // 1 MB
    u16*  W1T   = (u16*)w;  w += NH * NF * 2;
    u16*  W2T   = (u16*)w;  w += NC * NH * 2;
    u16*  idx   = (u16*)w;  w += (size_t)NB * NN * CST * 2;          // 5.25 MB

    kpre    <<<NB * 64 + 4 + NB * NN, 256, 0, stream>>>(X, A, a1s, a1d, W1, W2,
                                                        Xbf, W1T, W2T, FS1, FD1,
                                                        dvec, cntv, idx);
    kgat1   <<<dim3(NN / 8, NB), 512, 0, stream>>>(idx, cntv, FS1, FD1, dvec, Xbf,
                                                   W1T, W2T, b1, a2s, a2d,
                                                   FS2, FD2, OW2row);
    kgat2   <<<dim3(NN / 8, NB), 512, 0, stream>>>(idx, cntv, FS2, FD2, dvec,
                                                   OW2row, b2, node, gpart);
    kgraph2 <<<NB, 256, 0, stream>>>(gpart, graph);
}

// Round 7
// 95.867 us; speedup vs baseline: 1.1317x; 1.1294x over previous
//
#include <hip/hip_runtime.h>

// ---------------------------------------------------------------------------
// TwoLayerGCN on MI355X (gfx950).  B=4, N=2048, F=128, H=256, C=64.
//
//   d_i = rsqrt(nnz_i + 1) ; w_ij = [A_ij>0] exp(lrelu(fs_i+fd_j)) d_j (1+[i==j])
//   rs_i = sum_j [A_ij>0] exp(lrelu(fs_i+fd_j))
//   layer1: out1 = relu( (d_i/rs_i)(W@X)@W1 + b1 )
//   layer2: node = (d_i/rs_i) W2mat@(out1@W2) + b2 ; graph = sum_i node
//
// R5: CSR row-gather SpMM (A ~9.75% dense), CSR built during the one A read.
// R6 was latency-serialized: 8B gathers + per-step in-order ds_read (120cy) +
// VMEM (200cy) with 20cy work. R7: 16B loads (quarter-wave per nbr in L1,
// eighth-wave in L2), LDS reads + global loads batched 4-deep in named regs,
// (fd_j,d_j) packed as one float2 gather. No barriers in hot loop.
// ---------------------------------------------------------------------------

typedef __attribute__((ext_vector_type(8))) short  s16x8;
typedef __attribute__((ext_vector_type(4))) float  f32x4;
typedef unsigned short u16;
typedef unsigned int   u32;
typedef unsigned long long u64;

#define LOG2E 1.4426950408889634f
#define NB 4
#define NN 2048
#define NF 128
#define NH 256
#define NC 64
#define CST 320            // CSR row stride in u16 (max deg ~254)

__device__ __forceinline__ u16 f2bf(float f) {
    u32 x = __builtin_bit_cast(u32, f);
    return (u16)((x + 0x7fffu + ((x >> 16) & 1u)) >> 16);
}
__device__ __forceinline__ float bflo(u32 x) {
    return __builtin_bit_cast(float, x << 16);
}
__device__ __forceinline__ float bfhi(u32 x) {
    return __builtin_bit_cast(float, x & 0xffff0000u);
}
__device__ __forceinline__ u32 mbcnt64(u64 m) {
    return __builtin_amdgcn_mbcnt_hi((u32)(m >> 32),
           __builtin_amdgcn_mbcnt_lo((u32)m, 0));
}

// ---- kpre: block-role dispatch ---------------------------------------------
// [0,256): X rows -> Xbf + layer1 dots (FS1, FDD1.x).
// [256,260): W1T/W2T transposes.
// [260,260+8192): stats: A read -> CSR idx/cnt, d -> FDD1.y & FDD2.y.
__global__ void kpre(const float* __restrict__ X, const float* __restrict__ A,
                     const float* __restrict__ a1s, const float* __restrict__ a1d,
                     const float* __restrict__ W1, const float* __restrict__ W2,
                     u16* __restrict__ Xbf, u16* __restrict__ W1T,
                     u16* __restrict__ W2T, float* __restrict__ FS1,
                     float* __restrict__ FDD1, float* __restrict__ FDD2,
                     int* __restrict__ cnt, u16* __restrict__ idx) {
    const int bid = blockIdx.x;
    const int t = threadIdx.x;
    if (bid >= NB * 64 + 4) {                 // ---- stats role ----
        __shared__ u64 masks[32];
        __shared__ u32 basep[33];
        int row = bid - (NB * 64 + 4);        // 0..8191
        const float* Arow = A + (size_t)row * NN;
        int l = t & 63, wv = t >> 6;
#pragma unroll
        for (int e = 0; e < 8; e++) {
            float a = Arow[e * 256 + t];
            u64 m = __ballot(a > 0.f);
            if (l == 0) masks[e * 4 + wv] = m;
        }
        __syncthreads();
        if (t == 0) {
            u32 s = 0;
#pragma unroll
            for (int m = 0; m < 32; m++) { basep[m] = s; s += __popcll(masks[m]); }
            basep[32] = s;
            cnt[row] = (int)s;
            float d = rsqrtf((float)s + 1.0f);
            FDD1[2 * row + 1] = d;
            FDD2[2 * row + 1] = d;
        }
        __syncthreads();
#pragma unroll
        for (int s = 0; s < 8; s++) {
            int mi = wv * 8 + s;
            u64 m = masks[mi];
            if ((m >> l) & 1ull)
                idx[(size_t)row * CST + basep[mi] + mbcnt64(m)] = (u16)(mi * 64 + l);
        }
        return;
    }
    if (bid >= NB * 64) {                     // ---- weight role ----
        int tt = (bid - NB * 64) * 256 + t;
        for (int i = tt; i < NF * NH; i += 1024) {
            int k = i >> 8, c = i & 255;
            W1T[c * NF + k] = f2bf(W1[i]);
        }
        for (int i = tt; i < NH * NC; i += 1024) {
            int k = i >> 6, c = i & 63;
            W2T[c * NH + k] = f2bf(W2[i]);
        }
        return;
    }
    // ---- X role: 32 rows ----
    __shared__ float tile[32][132];
    __shared__ float asb[NF], adb[NF];
    __shared__ float dred[32][8][2];
    const int b = bid >> 6, i0 = (bid & 63) * 32;
    if (t < 128) asb[t] = a1s[t];
    else         adb[t - 128] = a1d[t - 128];
    for (int i = t; i < 32 * NF; i += 256) {
        int r = i >> 7, c = i & 127;
        tile[r][c] = X[((size_t)b * NN + i0 + r) * NF + c];
    }
    __syncthreads();
    {   // layer1 dots
        int r = t >> 3, ch = t & 7;
        float ps = 0.f, pd = 0.f;
#pragma unroll
        for (int q = 0; q < 16; q++) {
            float x = tile[r][ch * 16 + q];
            ps += x * asb[ch * 16 + q];
            pd += x * adb[ch * 16 + q];
        }
        dred[r][ch][0] = ps; dred[r][ch][1] = pd;
    }
    {   // Xbf row-major bf16
        int r = t >> 3, c = (t & 7) * 16;
        __attribute__((aligned(16))) u16 tmp[16];
#pragma unroll
        for (int q = 0; q < 16; q++) tmp[q] = f2bf(tile[r][c + q]);
        int4* dst = (int4*)&Xbf[((size_t)b * NN + i0 + r) * NF + c];
        const int4* sv = (const int4*)tmp;
        dst[0] = sv[0]; dst[1] = sv[1];
    }
    __syncthreads();
    if (t < 64) {
        int r = t & 31, which = t >> 5;
        float s = 0.f;
#pragma unroll
        for (int ch = 0; ch < 8; ch++) s += dred[r][ch][which];
        int grow = (b << 11) + i0 + r;
        if (which == 0) FS1[grow] = s * LOG2E;
        else            FDD1[2 * grow] = s * LOG2E;
    }
}

#define FMA8(W_, XV) { \
    float w_ = __builtin_bit_cast(float, W_); \
    accA[0] += w_ * bflo(XV.x); accA[1] += w_ * bfhi(XV.x); \
    accA[2] += w_ * bflo(XV.y); accA[3] += w_ * bfhi(XV.y); \
    accB[0] += w_ * bflo(XV.z); accB[1] += w_ * bfhi(XV.z); \
    accB[2] += w_ * bflo(XV.w); accB[3] += w_ * bfhi(XV.w); }

// ---- kgat1: gather layer1 + fused T@W1, dots2, out1@W2 ---------------------
// 8 waves x 1 row. Gather: quarter-wave (16 lanes x 16B) per nbr, 4 nbrs/step,
// LDS w/addr + global loads batched 4-deep. Epilogue: T'@W1 -> o1(relu+b1) ->
// {dots2 (waves 4-7) || o1@W2 -> OW2row (waves 0-3)}.
__global__ __launch_bounds__(512) void kgat1(
    const u16* __restrict__ idx, const int* __restrict__ cnt,
    const float* __restrict__ FS, const float* __restrict__ FDD,
    const u16* __restrict__ Xbf, const u16* __restrict__ W1T,
    const u16* __restrict__ W2T, const float* __restrict__ b1,
    const float* __restrict__ a2s, const float* __restrict__ a2d,
    float* __restrict__ FS2, float* __restrict__ FDD2,
    u16* __restrict__ OW2row) {
    const int b = blockIdx.y;
    const int i0 = blockIdx.x * 8;
    const int t = threadIdx.x, wv = t >> 6, l = t & 63;
    const int g = l >> 4, li = l & 15;
    const int h = l >> 5, hl = l & 31;
    const int qw = l >> 4, ql = l & 15;

    __shared__ uint2 wlds[8][64];
    __shared__ __attribute__((aligned(16))) u16 tlds[16][136];
    __shared__ __attribute__((aligned(16))) float o1[16][260];

    for (int z = t; z < 8 * 136; z += 512)     // zero pad rows 8..15 of T'
        ((u16*)tlds)[8 * 136 + z] = 0;

    const int row = i0 + wv;
    const int grow = (b << 11) + row;
    const float fs = FS[grow];
    const float* FDDb = FDD + ((size_t)(b << 11) << 1);
    const u16* irow = idx + (size_t)grow * CST;
    const int cn = cnt[grow];
    const char* Xb = (const char*)(Xbf + (size_t)b * NN * NF);

    f32x4 accA = {0.f, 0.f, 0.f, 0.f}, accB = {0.f, 0.f, 0.f, 0.f};
    float rs = 0.f;
    for (int p0 = 0; p0 < cn; p0 += 64) {
        int p = min(p0 + l, cn - 1);
        int j = irow[p];
        float2 fdd = *(const float2*)&FDDb[2 * j];
        float s = fs + fdd.x;
        float e = exp2f(fmaxf(s, 0.2f * s));
        e = (p0 + l < cn) ? e : 0.f;
        rs += e;
        float w = e * fdd.y * ((j == row) ? 2.f : 1.f);
        wlds[wv][l] = (uint2){__builtin_bit_cast(u32, w), (u32)j * (NF * 2)};
        int nq = min(64, cn - p0);
        for (int q = 0; q < nq; q += 16) {
            uint2 c0 = wlds[wv][q + qw];
            uint2 c1 = wlds[wv][q + 4 + qw];
            uint2 c2 = wlds[wv][q + 8 + qw];
            uint2 c3 = wlds[wv][q + 12 + qw];
            uint4 x0 = *(const uint4*)(Xb + c0.y + ql * 16);
            uint4 x1 = *(const uint4*)(Xb + c1.y + ql * 16);
            uint4 x2 = *(const uint4*)(Xb + c2.y + ql * 16);
            uint4 x3 = *(const uint4*)(Xb + c3.y + ql * 16);
            FMA8(c0.x, x0);
            FMA8(c1.x, x1);
            FMA8(c2.x, x2);
            FMA8(c3.x, x3);
        }
    }
#pragma unroll
    for (int r = 0; r < 4; r++) {
        accA[r] += __shfl_xor(accA[r], 16); accA[r] += __shfl_xor(accA[r], 32);
        accB[r] += __shfl_xor(accB[r], 16); accB[r] += __shfl_xor(accB[r], 32);
    }
#pragma unroll
    for (int o = 1; o < 64; o <<= 1) rs += __shfl_xor(rs, o);
    float rsc = FDDb[2 * row + 1] / fmaxf(rs, 1e-30f);
    if (qw == 0) {     // T' row: feats ql*8..+7, rsc pre-applied, bf16
        uint4 pk;
        pk.x = (u32)f2bf(accA[0] * rsc) | ((u32)f2bf(accA[1] * rsc) << 16);
        pk.y = (u32)f2bf(accA[2] * rsc) | ((u32)f2bf(accA[3] * rsc) << 16);
        pk.z = (u32)f2bf(accB[0] * rsc) | ((u32)f2bf(accB[1] * rsc) << 16);
        pk.w = (u32)f2bf(accB[2] * rsc) | ((u32)f2bf(accB[3] * rsc) << 16);
        *(uint4*)&tlds[wv][ql * 8] = pk;
    }
    __syncthreads();
    // GEMM1: o1[8][256] = T'[8pad16][128] @ W1 ; wave = 32 cols
    f32x4 zero = {0.f, 0.f, 0.f, 0.f};
    f32x4 p0a = zero, p1a = zero;
#pragma unroll
    for (int k2 = 0; k2 < 4; k2++) {
        s16x8 af = *(const s16x8*)&tlds[li][k2 * 32 + g * 8];
        s16x8 w0 = *(const s16x8*)&W1T[(size_t)(wv * 32 + li) * NF + k2 * 32 + g * 8];
        s16x8 w1 = *(const s16x8*)&W1T[(size_t)(wv * 32 + 16 + li) * NF + k2 * 32 + g * 8];
        p0a = __builtin_amdgcn_mfma_f32_16x16x32_bf16(af, w0, p0a, 0, 0, 0);
        p1a = __builtin_amdgcn_mfma_f32_16x16x32_bf16(af, w1, p1a, 0, 0, 0);
    }
#pragma unroll
    for (int r = 0; r < 4; r++) {   // rows g*4+r; g>=2 are pad rows -> 0
        int rr = g * 4 + r;
        int ca = wv * 32 + li, cb = ca + 16;
        o1[rr][ca] = (g < 2) ? fmaxf(p0a[r] + b1[ca], 0.f) : 0.f;
        o1[rr][cb] = (g < 2) ? fmaxf(p1a[r] + b1[cb], 0.f) : 0.f;
    }
    __syncthreads();
    if (wv >= 4) {     // dots2: 4 waves x 2 rows, 8 feats/lane-half
        int r = (wv - 4) * 2 + h;
        float ps = 0.f, pd = 0.f;
#pragma unroll
        for (int q = 0; q < 2; q++) {
            int c = hl * 8 + q * 4;
            float4 xv = *(const float4*)&o1[r][c];
            float4 sv = *(const float4*)&a2s[c];
            float4 dv = *(const float4*)&a2d[c];
            ps += xv.x * sv.x + xv.y * sv.y + xv.z * sv.z + xv.w * sv.w;
            pd += xv.x * dv.x + xv.y * dv.y + xv.z * dv.z + xv.w * dv.w;
        }
#pragma unroll
        for (int o = 1; o < 32; o <<= 1) {
            ps += __shfl_xor(ps, o); pd += __shfl_xor(pd, o);
        }
        if (hl == 0) {
            FS2[(b << 11) + i0 + r]        = ps * LOG2E;
            FDD2[2 * ((b << 11) + i0 + r)] = pd * LOG2E;
        }
    } else {           // GEMM2: OW2row[8][64] = o1[8pad16][256] @ W2 ; wave = 16 cols
        f32x4 q0 = zero;
#pragma unroll
        for (int k2 = 0; k2 < 8; k2++) {
            const float* op = &o1[li][k2 * 32 + g * 8];
            float4 v0 = *(const float4*)op;
            float4 v1 = *(const float4*)(op + 4);
            s16x8 aa;
            aa[0] = (short)f2bf(v0.x); aa[1] = (short)f2bf(v0.y);
            aa[2] = (short)f2bf(v0.z); aa[3] = (short)f2bf(v0.w);
            aa[4] = (short)f2bf(v1.x); aa[5] = (short)f2bf(v1.y);
            aa[6] = (short)f2bf(v1.z); aa[7] = (short)f2bf(v1.w);
            s16x8 bb = *(const s16x8*)&W2T[(size_t)(wv * 16 + li) * NH + k2 * 32 + g * 8];
            q0 = __builtin_amdgcn_mfma_f32_16x16x32_bf16(aa, bb, q0, 0, 0, 0);
        }
        if (g < 2) {
#pragma unroll
            for (int r = 0; r < 4; r++) {
                int rr = g * 4 + r;
                OW2row[((size_t)(b << 11) + i0 + rr) * NC + wv * 16 + li] = f2bf(q0[r]);
            }
        }
    }
}

// ---- kgat2: gather layer2 on OW2 rows; node + graph partials ---------------
// eighth-wave (8 lanes x 16B) per nbr, 8 nbrs/step, 2-deep batches.
__global__ __launch_bounds__(512) void kgat2(
    const u16* __restrict__ idx, const int* __restrict__ cnt,
    const float* __restrict__ FS, const float* __restrict__ FDD,
    const u16* __restrict__ OW2row, const float* __restrict__ b2,
    float* __restrict__ node, float* __restrict__ gpart) {
    const int b = blockIdx.y;
    const int i0 = blockIdx.x * 8;
    const int t = threadIdx.x, wv = t >> 6, l = t & 63;
    const int ow = l >> 3, ol = l & 7;
    __shared__ uint2 wlds[8][64];
    __shared__ float gsm[8][64];

    const int row = i0 + wv;
    const int grow = (b << 11) + row;
    const float fs = FS[grow];
    const float* FDDb = FDD + ((size_t)(b << 11) << 1);
    const u16* irow = idx + (size_t)grow * CST;
    const int cn = cnt[grow];
    const char* Ob = (const char*)(OW2row + (size_t)(b << 11) * NC);

    f32x4 accA = {0.f, 0.f, 0.f, 0.f}, accB = {0.f, 0.f, 0.f, 0.f};
    float rs = 0.f;
    for (int p0 = 0; p0 < cn; p0 += 64) {
        int p = min(p0 + l, cn - 1);
        int j = irow[p];
        float2 fdd = *(const float2*)&FDDb[2 * j];
        float s = fs + fdd.x;
        float e = exp2f(fmaxf(s, 0.2f * s));
        e = (p0 + l < cn) ? e : 0.f;
        rs += e;
        float w = e * fdd.y * ((j == row) ? 2.f : 1.f);
        wlds[wv][l] = (uint2){__builtin_bit_cast(u32, w), (u32)j * (NC * 2)};
        int nq = min(64, cn - p0);
        for (int q = 0; q < nq; q += 16) {
            uint2 c0 = wlds[wv][q + ow];
            uint2 c1 = wlds[wv][q + 8 + ow];
            uint4 x0 = *(const uint4*)(Ob + c0.y + ol * 16);
            uint4 x1 = *(const uint4*)(Ob + c1.y + ol * 16);
            FMA8(c0.x, x0);
            FMA8(c1.x, x1);
        }
    }
#pragma unroll
    for (int r = 0; r < 4; r++) {
        accA[r] += __shfl_xor(accA[r], 8);
        accA[r] += __shfl_xor(accA[r], 16); accA[r] += __shfl_xor(accA[r], 32);
        accB[r] += __shfl_xor(accB[r], 8);
        accB[r] += __shfl_xor(accB[r], 16); accB[r] += __shfl_xor(accB[r], 32);
    }
#pragma unroll
    for (int o = 1; o < 64; o <<= 1) rs += __shfl_xor(rs, o);
    float rsc = FDDb[2 * row + 1] / fmaxf(rs, 1e-30f);
    if (ow == 0) {     // lane ol: feats ol*8..+7
        int c = ol * 8;
        float4 b2a = *(const float4*)&b2[c];
        float4 b2b = *(const float4*)&b2[c + 4];
        float4 va = {accA[0] * rsc + b2a.x, accA[1] * rsc + b2a.y,
                     accA[2] * rsc + b2a.z, accA[3] * rsc + b2a.w};
        float4 vb = {accB[0] * rsc + b2b.x, accB[1] * rsc + b2b.y,
                     accB[2] * rsc + b2b.z, accB[3] * rsc + b2b.w};
        *(float4*)&node[(size_t)grow * NC + c]     = va;
        *(float4*)&node[(size_t)grow * NC + c + 4] = vb;
        *(float4*)&gsm[wv][c]     = va;
        *(float4*)&gsm[wv][c + 4] = vb;
    }
    __syncthreads();
    if (t < NC) {
        float s = 0.f;
#pragma unroll
        for (int r = 0; r < 8; r++) s += gsm[r][t];
        gpart[(((size_t)b * (NN / 8)) + blockIdx.x) * NC + t] = s;
    }
}

// ---- graph scores: reduce per-block partials -------------------------------
__global__ void kgraph2(const float* __restrict__ gpart, float* __restrict__ graph) {
    int b = blockIdx.x;
    int c = threadIdx.x & 63, ch = threadIdx.x >> 6;
    float s = 0.f;
    for (int p = ch; p < NN / 8; p += 4)
        s += gpart[(((size_t)b * (NN / 8)) + p) * NC + c];
    __shared__ float red[4][64];
    red[ch][c] = s;
    __syncthreads();
    if (ch == 0) graph[b * NC + c] = red[0][c] + red[1][c] + red[2][c] + red[3][c];
}

extern "C" void kernel_launch(void* const* d_in, const int* in_sizes, int n_in,
                              void* d_out, int out_size, void* d_ws, size_t ws_size,
                              hipStream_t stream) {
    const float* X   = (const float*)d_in[0];
    const float* A   = (const float*)d_in[1];
    const float* a1s = (const float*)d_in[2];
    const float* a1d = (const float*)d_in[3];
    const float* W1  = (const float*)d_in[4];
    const float* b1  = (const float*)d_in[5];
    const float* a2s = (const float*)d_in[6];
    const float* a2d = (const float*)d_in[7];
    const float* W2  = (const float*)d_in[8];
    const float* b2  = (const float*)d_in[9];

    float* node  = (float*)d_out;                 // [4][2048][64]
    float* graph = node + (size_t)NB * NN * NC;   // [4][64]

    char* w = (char*)d_ws;
    float* FS1  = (float*)w; w += NB * NN * 4;
    float* FDD1 = (float*)w; w += NB * NN * 8;    // (fd1_j, d_j) pairs
    float* FS2  = (float*)w; w += NB * NN * 4;
    float* FDD2 = (float*)w; w += NB * NN * 8;    // (fd2_j, d_j) pairs
    int*  cntv  = (int*)w;  w += NB * NN * 4;
    float* gpart = (float*)w; w += (size_t)NB * (NN / 8) * NC * 4;   // 256 KB
    u16*  Xbf   = (u16*)w;  w += (size_t)NB * NN * NF * 2;           // 2 MB
    u16*  OW2row = (u16*)w; w += (size_t)NB * NN * NC * 2;           // 1 MB
    u16*  W1T   = (u16*)w;  w += NH * NF * 2;
    u16*  W2T   = (u16*)w;  w += NC * NH * 2;
    u16*  idx   = (u16*)w;  w += (size_t)NB * NN * CST * 2;          // 5.25 MB

    kpre    <<<NB * 64 + 4 + NB * NN, 256, 0, stream>>>(X, A, a1s, a1d, W1, W2,
                                                        Xbf, W1T, W2T, FS1,
                                                        FDD1, FDD2, cntv, idx);
    kgat1   <<<dim3(NN / 8, NB), 512, 0, stream>>>(idx, cntv, FS1, FDD1, Xbf,
                                                   W1T, W2T, b1, a2s, a2d,
                                                   FS2, FDD2, OW2row);
    kgat2   <<<dim3(NN / 8, NB), 512, 0, stream>>>(idx, cntv, FS2, FDD2,
                                                   OW2row, b2, node, gpart);
    kgraph2 <<<NB, 256, 0, stream>>>(gpart, graph);
}